// Round 7
// baseline (301.410 us; speedup 1.0000x reference)
//
#include <hip/hip_runtime.h>
#include <math.h>

// Problem constants
#define B_  4
#define C_  256
#define N_  4096
#define CK_ 32
#define CV_ 128

typedef __attribute__((ext_vector_type(8))) short short8;   // 8 bf16 (x32 A/B frag)
typedef __attribute__((ext_vector_type(4))) float f32x4;    // MFMA C/D frag
typedef unsigned short u16;
typedef unsigned int   u32;

static constexpr float LOG2E = 1.4426950408889634f;

static __device__ __forceinline__ u16 f2bf(float f) {       // fp32 -> bf16 RNE
    u32 u = __float_as_uint(f);
    u = (u + 0x7FFFu + ((u >> 16) & 1u)) >> 16;
    return (u16)u;
}
static __device__ __forceinline__ float bf2f(u16 h) {
    return __uint_as_float(((u32)h) << 16);
}
// fast pack of two positive floats to bf16x2 (round-half-up)
static __device__ __forceinline__ u32 pack2bf(float a, float b) {
    const u32 ua = (__float_as_uint(a) + 0x8000u) >> 16;
    const u32 ub = (__float_as_uint(b) + 0x8000u) & 0xFFFF0000u;
    return ua | ub;
}
// wait lgkmcnt(0) ONLY (vmcnt/expcnt stay open)
static __device__ __forceinline__ void wait_lds() {
    __builtin_amdgcn_s_waitcnt(0xC07F);
}

// ---------------------------------------------------------------------------
// Kernel 0a: weight convert. W16[192][256] = [theta*log2e; phi; g] bf16,
// ow16[256][128] bf16.
// ---------------------------------------------------------------------------
__global__ __launch_bounds__(256) void wconv_kernel(
    const float* __restrict__ theta_w, const float* __restrict__ phi_w,
    const float* __restrict__ g_w,     const float* __restrict__ o_w,
    u16* __restrict__ W16, u16* __restrict__ ow16)
{
    const int idx = blockIdx.x * 256 + threadIdx.x;
    if (idx < 8192)        W16[idx] = f2bf(theta_w[idx] * LOG2E);
    else if (idx < 16384)  W16[idx] = f2bf(phi_w[idx - 8192]);
    else if (idx < 49152)  W16[idx] = f2bf(g_w[idx - 16384]);
    else                   ow16[idx - 49152] = f2bf(o_w[idx - 49152]);
}

// ---------------------------------------------------------------------------
// Kernel 0b: x [B][C][N] fp32 -> xT16 [B][N][C] bf16 (transpose + convert).
// ---------------------------------------------------------------------------
__global__ __launch_bounds__(256) void xt_kernel(
    const float* __restrict__ x, u16* __restrict__ xT16)
{
    const int b = blockIdx.z, c0 = blockIdx.y * 64, n0 = blockIdx.x * 64;
    const int t = threadIdx.x;
    __shared__ float tile[64][65];

    const int cr = t >> 4, nc = (t & 15) * 4;
    #pragma unroll
    for (int it = 0; it < 4; ++it) {
        const float4 v = *(const float4*)(x + (size_t)(b * C_ + c0 + cr + it * 16) * N_ + n0 + nc);
        tile[cr + it * 16][nc + 0] = v.x; tile[cr + it * 16][nc + 1] = v.y;
        tile[cr + it * 16][nc + 2] = v.z; tile[cr + it * 16][nc + 3] = v.w;
    }
    __syncthreads();
    const int n = t >> 2, cg = (t & 3) * 16;
    union { u16 us[16]; uint4 u4[2]; } pk;
    #pragma unroll
    for (int e = 0; e < 16; ++e) pk.us[e] = f2bf(tile[cg + e][n]);
    uint4* dst = (uint4*)(xT16 + (size_t)(b * N_ + n0 + n) * C_ + c0 + cg);
    dst[0] = pk.u4[0]; dst[1] = pk.u4[1];
}

// ---------------------------------------------------------------------------
// Kernel 1: projections via MFMA, phase-split for parallelism.
// Grid (N/64, 3, B): y=0 -> theta/phi; y=1 -> g rows 0..63; y=2 -> g 64..127.
// ---------------------------------------------------------------------------
__global__ __launch_bounds__(256) void proj_mfma_kernel(
    const u16* __restrict__ xT16, const u16* __restrict__ W16,
    const float* __restrict__ theta_b, const float* __restrict__ phi_b,
    const float* __restrict__ g_b,
    u16* __restrict__ theta_t, u16* __restrict__ phi_t, u16* __restrict__ g16)
{
    const int b = blockIdx.z, n0 = blockIdx.x * 64, phase = blockIdx.y;
    const int w = threadIdx.x >> 6, lane = threadIdx.x & 63;
    const int lr = lane & 15, q = lane >> 4;
    const f32x4 zf = {0.f, 0.f, 0.f, 0.f};

    if (phase == 0) {
        const u16* xrow = xT16 + (size_t)(b * N_ + n0 + w * 16 + lr) * C_;
        f32x4 acc[4];
        #pragma unroll
        for (int nt = 0; nt < 4; ++nt) acc[nt] = zf;
        for (int ks = 0; ks < 8; ++ks) {
            const short8 aX = *(const short8*)(xrow + ks * 32 + q * 8);
            #pragma unroll
            for (int nt = 0; nt < 4; ++nt) {
                const short8 bW = *(const short8*)(W16 + (size_t)(nt * 16 + lr) * C_ + ks * 32 + q * 8);
                acc[nt] = __builtin_amdgcn_mfma_f32_16x16x32_bf16(aX, bW, acc[nt], 0, 0, 0);
            }
        }
        #pragma unroll
        for (int nt = 0; nt < 4; ++nt) {
            const int o = nt * 16 + lr;
            #pragma unroll
            for (int reg = 0; reg < 4; ++reg) {
                const int n = n0 + w * 16 + q * 4 + reg;
                if (nt < 2)
                    theta_t[(size_t)(b * N_ + n) * CK_ + o] = f2bf(acc[nt][reg] + theta_b[o] * LOG2E);
                else
                    phi_t[(size_t)(b * N_ + n) * CK_ + (o - 32)] = f2bf(acc[nt][reg] + phi_b[o - 32]);
            }
        }
    } else {
        const int crow = (phase - 1) * 64 + w * 16;
        f32x4 ag[4];
        #pragma unroll
        for (int nt = 0; nt < 4; ++nt) ag[nt] = zf;
        for (int ks = 0; ks < 8; ++ks) {
            const short8 aW = *(const short8*)(W16 + (size_t)(64 + crow + lr) * C_ + ks * 32 + q * 8);
            #pragma unroll
            for (int nt = 0; nt < 4; ++nt) {
                const short8 bX = *(const short8*)(xT16 + (size_t)(b * N_ + n0 + nt * 16 + lr) * C_ + ks * 32 + q * 8);
                ag[nt] = __builtin_amdgcn_mfma_f32_16x16x32_bf16(aW, bX, ag[nt], 0, 0, 0);
            }
        }
        #pragma unroll
        for (int nt = 0; nt < 4; ++nt) {
            #pragma unroll
            for (int reg = 0; reg < 4; ++reg) {
                const int c = crow + q * 4 + reg;
                const int n = n0 + nt * 16 + lr;
                g16[(size_t)(b * CV_ + c) * N_ + n] = f2bf(ag[nt][reg] + g_b[c]);
            }
        }
    }
}

// ---------------------------------------------------------------------------
// Kernel 2: Z[b][j] = sum_i exp2(S[i][j]) via MFMA.
// ---------------------------------------------------------------------------
__global__ __launch_bounds__(256) void colstats_kernel(
    const u16* __restrict__ theta_t, const u16* __restrict__ phi_t,
    float* __restrict__ Z)
{
    const int b  = blockIdx.z;
    const int j0 = blockIdx.x * 32;
    const int istart = blockIdx.y * (N_ / 4);
    const int tid = threadIdx.x;
    const int wave = tid >> 6, lane = tid & 63;
    const int lr = lane & 15, q = lane >> 4;

    const int jW = j0 + (wave & 1) * 16;
    const short8 bF = *(const short8*)(phi_t + (size_t)(b * N_ + jW + lr) * CK_ + q * 8);

    const u16* thp = theta_t + (size_t)b * N_ * CK_;
    const f32x4 zero = {0.f, 0.f, 0.f, 0.f};
    float zacc = 0.f;
    for (int it = istart + (wave >> 1) * 16; it < istart + N_ / 4; it += 32) {
        const short8 aF = *(const short8*)(thp + (size_t)(it + lr) * CK_ + q * 8);
        f32x4 S = __builtin_amdgcn_mfma_f32_16x16x32_bf16(aF, bF, zero, 0, 0, 0);
        zacc += exp2f(S[0]) + exp2f(S[1]) + exp2f(S[2]) + exp2f(S[3]);
    }
    zacc += __shfl_xor(zacc, 16);
    zacc += __shfl_xor(zacc, 32);
    if (lane < 16) atomicAdd(&Z[(size_t)b * N_ + jW + lr], zacc);
}

// ---------------------------------------------------------------------------
// Kernel 4: o_pre partial = sum_{j in quarter} g[c][j] * exp2(S[i][j]) / Z[j]
// Wave-private LDS, no barriers. Wave = 16 i x 128 c -> 4096 waves total
// (16 waves/CU, 2x R6). LDS row = i (16 rows x 64 u16, bank-aligned),
// 16B chunks XOR-swizzled (chunk ^ (row&7)) -> conflict-free writes+b128
// reads (R3-verified pattern). Epilogue stores direct to global.
// Grid (N/64, 4 j-quarters, B) = 1024 blocks x 256 thr.
// ---------------------------------------------------------------------------
__global__ __launch_bounds__(256, 4) void opre_kernel(
    const u16* __restrict__ theta_t, const u16* __restrict__ phi_t,
    const u16* __restrict__ g16, const float* __restrict__ Z,
    u16* __restrict__ o_p)
{
    const int b = blockIdx.z, jh = blockIdx.y;
    const int w = threadIdx.x >> 6, lane = threadIdx.x & 63;
    const int lr = lane & 15, q = lane >> 4;
    const int iw = blockIdx.x * 64 + w * 16;          // wave's 16-i strip

    __shared__ u16 El[4][16 * 64];                    // 2 KB per wave
    u16* Ew = El[w];

    // theta B-frag (n=i), invariant over j
    const short8 thB = *(const short8*)(theta_t + (size_t)(b * N_ + iw + lr) * CK_ + q * 8);

    f32x4 acc[8];                                     // [c-tile], 32 regs
    #pragma unroll
    for (int ct = 0; ct < 8; ++ct) acc[ct] = (f32x4){0.f, 0.f, 0.f, 0.f};

    const f32x4 zf = {0.f, 0.f, 0.f, 0.f};
    const u16* pb = phi_t + (size_t)(b * N_) * CK_;
    const float* Zb = Z + (size_t)b * N_;
    const u16* gbase = g16 + (size_t)(b * CV_) * N_;
    const int jstart = jh * (N_ / 4);

    for (int j0 = jstart; j0 < jstart + N_ / 4; j0 += 64) {
        // phi A-frags for this 64-j chunk (all 4 waves load same -> L1 reuse)
        short8 phA[4];
        #pragma unroll
        for (int jt = 0; jt < 4; ++jt)
            phA[jt] = *(const short8*)(pb + (size_t)(j0 + jt * 16 + lr) * CK_ + q * 8);

        // S (A=phi m=j, B=theta n=i) -> lane holds E(i=lr, j=jt*16+q*4+reg)
        // -> exp2/Z -> 8B write into swizzled wave-private LDS row i=lr
        #pragma unroll
        for (int jt = 0; jt < 4; ++jt) {
            const float4 zq = *(const float4*)(Zb + j0 + jt * 16 + q * 4);
            const f32x4 S = __builtin_amdgcn_mfma_f32_16x16x32_bf16(phA[jt], thB, zf, 0, 0, 0);
            const float e0 = exp2f(S[0]) * __builtin_amdgcn_rcpf(zq.x);
            const float e1 = exp2f(S[1]) * __builtin_amdgcn_rcpf(zq.y);
            const float e2 = exp2f(S[2]) * __builtin_amdgcn_rcpf(zq.z);
            const float e3 = exp2f(S[3]) * __builtin_amdgcn_rcpf(zq.w);
            uint2 ev;
            ev.x = pack2bf(e0, e1);
            ev.y = pack2bf(e2, e3);
            const int chunkL = jt * 2 + (q >> 1);
            *(uint2*)(Ew + lr * 64 + ((chunkL ^ (lr & 7)) << 3) + (q & 1) * 4) = ev;
        }
        wait_lds();   // own-wave DS writes complete before reads

        // PV: acc[ct] += g(c,j) . E(i,j);  A = g (m=c), B = E (n=i, k=j)
        #pragma unroll
        for (int j32 = 0; j32 < 2; ++j32) {
            const int chunkR = j32 * 4 + q;
            const short8 bE = *(const short8*)(Ew + lr * 64 + ((chunkR ^ (lr & 7)) << 3));
            #pragma unroll
            for (int ct = 0; ct < 8; ++ct) {
                const short8 gA = *(const short8*)(gbase + (size_t)(ct * 16 + lr) * N_ + j0 + j32 * 32 + q * 8);
                acc[ct] = __builtin_amdgcn_mfma_f32_16x16x32_bf16(gA, bE, acc[ct], 0, 0, 0);
            }
        }
        // same-wave DS FIFO ordering: next chunk's writes queue after these
        // reads -> no extra wait needed before overwriting Ew.
    }

    // epilogue: lane holds o_pre(c = ct*16 + q*4 + reg, i = iw + lr).
    // Direct bf16 stores: [n][cv], 8 B per lane, 16 rows x 32 B segments.
    u16* op = o_p + (size_t)(jh * B_ + b) * N_ * CV_ + (size_t)(iw + lr) * CV_;
    #pragma unroll
    for (int ct = 0; ct < 8; ++ct) {
        union { u16 us[4]; uint2 u2; } pk;
        #pragma unroll
        for (int reg = 0; reg < 4; ++reg) pk.us[reg] = f2bf(acc[ct][reg]);
        *(uint2*)(op + ct * 16 + q * 4) = pk.u2;
    }
}

// ---------------------------------------------------------------------------
// Kernel 5: out = x + gamma * (o_w @ sum_p o_p + o_b) via MFMA.
// Grid (N/64, 4 oc-quarters, B) = 1024 blocks. Wave: 1 oc m-tile x 64 n.
// ---------------------------------------------------------------------------
__global__ __launch_bounds__(256) void final_mfma_kernel(
    const u16* __restrict__ o_p, const u16* __restrict__ ow16,
    const float* __restrict__ o_b, const float* __restrict__ gamma,
    const float* __restrict__ x, float* __restrict__ out)
{
    const int b = blockIdx.z, ych = blockIdx.y, n0 = blockIdx.x * 64;
    const int w = threadIdx.x >> 6, lane = threadIdx.x & 63;
    const int lr = lane & 15, q = lane >> 4;
    const size_t PSTRIDE = (size_t)B_ * N_ * CV_;

    f32x4 acc[4];
    #pragma unroll
    for (int nt = 0; nt < 4; ++nt) acc[nt] = (f32x4){0.f, 0.f, 0.f, 0.f};

    const int ocb = ych * 64 + w * 16;

    for (int ks = 0; ks < 4; ++ks) {
        const short8 aW = *(const short8*)(ow16 + (size_t)(ocb + lr) * CV_ + ks * 32 + q * 8);
        #pragma unroll
        for (int nt = 0; nt < 4; ++nt) {
            const size_t pbase = (size_t)(b * N_ + n0 + nt * 16 + lr) * CV_ + ks * 32 + q * 8;
            float s[8] = {0.f, 0.f, 0.f, 0.f, 0.f, 0.f, 0.f, 0.f};
            #pragma unroll
            for (int part = 0; part < 4; ++part) {
                const uint4 raw = *(const uint4*)(o_p + part * PSTRIDE + pbase);
                const u16* pr = (const u16*)&raw;
                #pragma unroll
                for (int e = 0; e < 8; ++e) s[e] += bf2f(pr[e]);
            }
            union { u16 us[8]; short8 s8; } pk;
            #pragma unroll
            for (int e = 0; e < 8; ++e) pk.us[e] = f2bf(s[e]);
            acc[nt] = __builtin_amdgcn_mfma_f32_16x16x32_bf16(aW, pk.s8, acc[nt], 0, 0, 0);
        }
    }

    const float gm = gamma[0];
    #pragma unroll
    for (int nt = 0; nt < 4; ++nt) {
        #pragma unroll
        for (int reg = 0; reg < 4; ++reg) {
            const int oc = ocb + q * 4 + reg;
            const int n = n0 + nt * 16 + lr;
            const size_t off = (size_t)(b * C_ + oc) * N_ + n;
            out[off] = x[off] + gm * (acc[nt][reg] + o_b[oc]);
        }
    }
}

// ---------------------------------------------------------------------------
extern "C" void kernel_launch(void* const* d_in, const int* in_sizes, int n_in,
                              void* d_out, int out_size, void* d_ws, size_t ws_size,
                              hipStream_t stream)
{
    const float* x       = (const float*)d_in[0];
    const float* theta_w = (const float*)d_in[1];
    const float* theta_b = (const float*)d_in[2];
    const float* phi_w   = (const float*)d_in[3];
    const float* phi_b   = (const float*)d_in[4];
    const float* g_w     = (const float*)d_in[5];
    const float* g_b     = (const float*)d_in[6];
    const float* o_w     = (const float*)d_in[7];
    const float* o_b     = (const float*)d_in[8];
    const float* gamma   = (const float*)d_in[9];
    float* out = (float*)d_out;

    // workspace: xT16 8MB | W16 96KB | ow16 64KB | theta_t 1MB | phi_t 1MB |
    //            g16 4MB | Z 64KB | o_p 4x4MB bf16 = 16MB    (~30.2 MB)
    u16* xT16    = (u16*)d_ws;
    u16* W16     = xT16 + (size_t)B_ * N_ * C_;
    u16* ow16    = W16 + 192 * C_;
    u16* theta_t = ow16 + C_ * CV_;
    u16* phi_t   = theta_t + (size_t)B_ * N_ * CK_;
    u16* g16     = phi_t + (size_t)B_ * N_ * CK_;
    float* Z     = (float*)(g16 + (size_t)B_ * CV_ * N_);
    u16* o_p     = (u16*)(Z + (size_t)B_ * N_);

    (void)hipMemsetAsync(Z, 0, (size_t)B_ * N_ * sizeof(float), stream);

    wconv_kernel<<<dim3(320), 256, 0, stream>>>(theta_w, phi_w, g_w, o_w, W16, ow16);
    xt_kernel<<<dim3(N_ / 64, C_ / 64, B_), 256, 0, stream>>>(x, xT16);
    proj_mfma_kernel<<<dim3(N_ / 64, 3, B_), 256, 0, stream>>>(
        xT16, W16, theta_b, phi_b, g_b, theta_t, phi_t, g16);
    colstats_kernel<<<dim3(N_ / 32, 4, B_), 256, 0, stream>>>(theta_t, phi_t, Z);
    opre_kernel<<<dim3(N_ / 64, 4, B_), 256, 0, stream>>>(theta_t, phi_t, g16, Z, o_p);
    final_mfma_kernel<<<dim3(N_ / 64, 4, B_), 256, 0, stream>>>(
        o_p, ow16, o_b, gamma, x, out);
}

// Round 8
// 219.715 us; speedup vs baseline: 1.3718x; 1.3718x over previous
//
#include <hip/hip_runtime.h>
#include <math.h>

// Problem constants
#define B_  4
#define C_  256
#define N_  4096
#define CK_ 32
#define CV_ 128

typedef __attribute__((ext_vector_type(8))) short short8;   // 8 bf16 (x32 A/B frag)
typedef __attribute__((ext_vector_type(4))) float f32x4;    // MFMA C/D frag
typedef unsigned short u16;
typedef unsigned int   u32;

static constexpr float LOG2E = 1.4426950408889634f;

static __device__ __forceinline__ u16 f2bf(float f) {       // fp32 -> bf16 RNE
    u32 u = __float_as_uint(f);
    u = (u + 0x7FFFu + ((u >> 16) & 1u)) >> 16;
    return (u16)u;
}
static __device__ __forceinline__ float bf2f(u16 h) {
    return __uint_as_float(((u32)h) << 16);
}

// ---------------------------------------------------------------------------
// Kernel 0a: weight convert. W16[192][256] = [theta*log2e; phi; g] bf16,
// ow16[256][128] bf16.
// ---------------------------------------------------------------------------
__global__ __launch_bounds__(256) void wconv_kernel(
    const float* __restrict__ theta_w, const float* __restrict__ phi_w,
    const float* __restrict__ g_w,     const float* __restrict__ o_w,
    u16* __restrict__ W16, u16* __restrict__ ow16)
{
    const int idx = blockIdx.x * 256 + threadIdx.x;
    if (idx < 8192)        W16[idx] = f2bf(theta_w[idx] * LOG2E);
    else if (idx < 16384)  W16[idx] = f2bf(phi_w[idx - 8192]);
    else if (idx < 49152)  W16[idx] = f2bf(g_w[idx - 16384]);
    else                   ow16[idx - 49152] = f2bf(o_w[idx - 49152]);
}

// ---------------------------------------------------------------------------
// Kernel 0b: x [B][C][N] fp32 -> xT16 [B][N][C] bf16 (transpose + convert).
// ---------------------------------------------------------------------------
__global__ __launch_bounds__(256) void xt_kernel(
    const float* __restrict__ x, u16* __restrict__ xT16)
{
    const int b = blockIdx.z, c0 = blockIdx.y * 64, n0 = blockIdx.x * 64;
    const int t = threadIdx.x;
    __shared__ float tile[64][65];

    const int cr = t >> 4, nc = (t & 15) * 4;
    #pragma unroll
    for (int it = 0; it < 4; ++it) {
        const float4 v = *(const float4*)(x + (size_t)(b * C_ + c0 + cr + it * 16) * N_ + n0 + nc);
        tile[cr + it * 16][nc + 0] = v.x; tile[cr + it * 16][nc + 1] = v.y;
        tile[cr + it * 16][nc + 2] = v.z; tile[cr + it * 16][nc + 3] = v.w;
    }
    __syncthreads();
    const int n = t >> 2, cg = (t & 3) * 16;
    union { u16 us[16]; uint4 u4[2]; } pk;
    #pragma unroll
    for (int e = 0; e < 16; ++e) pk.us[e] = f2bf(tile[cg + e][n]);
    uint4* dst = (uint4*)(xT16 + (size_t)(b * N_ + n0 + n) * C_ + c0 + cg);
    dst[0] = pk.u4[0]; dst[1] = pk.u4[1];
}

// ---------------------------------------------------------------------------
// Kernel 1: projections via MFMA, phase-split for parallelism.
// Grid (N/64, 3, B): y=0 -> theta/phi; y=1 -> g rows 0..63; y=2 -> g 64..127.
// ---------------------------------------------------------------------------
__global__ __launch_bounds__(256) void proj_mfma_kernel(
    const u16* __restrict__ xT16, const u16* __restrict__ W16,
    const float* __restrict__ theta_b, const float* __restrict__ phi_b,
    const float* __restrict__ g_b,
    u16* __restrict__ theta_t, u16* __restrict__ phi_t, u16* __restrict__ g16)
{
    const int b = blockIdx.z, n0 = blockIdx.x * 64, phase = blockIdx.y;
    const int w = threadIdx.x >> 6, lane = threadIdx.x & 63;
    const int lr = lane & 15, q = lane >> 4;
    const f32x4 zf = {0.f, 0.f, 0.f, 0.f};

    if (phase == 0) {
        const u16* xrow = xT16 + (size_t)(b * N_ + n0 + w * 16 + lr) * C_;
        f32x4 acc[4];
        #pragma unroll
        for (int nt = 0; nt < 4; ++nt) acc[nt] = zf;
        for (int ks = 0; ks < 8; ++ks) {
            const short8 aX = *(const short8*)(xrow + ks * 32 + q * 8);
            #pragma unroll
            for (int nt = 0; nt < 4; ++nt) {
                const short8 bW = *(const short8*)(W16 + (size_t)(nt * 16 + lr) * C_ + ks * 32 + q * 8);
                acc[nt] = __builtin_amdgcn_mfma_f32_16x16x32_bf16(aX, bW, acc[nt], 0, 0, 0);
            }
        }
        #pragma unroll
        for (int nt = 0; nt < 4; ++nt) {
            const int o = nt * 16 + lr;
            #pragma unroll
            for (int reg = 0; reg < 4; ++reg) {
                const int n = n0 + w * 16 + q * 4 + reg;
                if (nt < 2)
                    theta_t[(size_t)(b * N_ + n) * CK_ + o] = f2bf(acc[nt][reg] + theta_b[o] * LOG2E);
                else
                    phi_t[(size_t)(b * N_ + n) * CK_ + (o - 32)] = f2bf(acc[nt][reg] + phi_b[o - 32]);
            }
        }
    } else {
        const int crow = (phase - 1) * 64 + w * 16;
        f32x4 ag[4];
        #pragma unroll
        for (int nt = 0; nt < 4; ++nt) ag[nt] = zf;
        for (int ks = 0; ks < 8; ++ks) {
            const short8 aW = *(const short8*)(W16 + (size_t)(64 + crow + lr) * C_ + ks * 32 + q * 8);
            #pragma unroll
            for (int nt = 0; nt < 4; ++nt) {
                const short8 bX = *(const short8*)(xT16 + (size_t)(b * N_ + n0 + nt * 16 + lr) * C_ + ks * 32 + q * 8);
                ag[nt] = __builtin_amdgcn_mfma_f32_16x16x32_bf16(aW, bX, ag[nt], 0, 0, 0);
            }
        }
        #pragma unroll
        for (int nt = 0; nt < 4; ++nt) {
            #pragma unroll
            for (int reg = 0; reg < 4; ++reg) {
                const int c = crow + q * 4 + reg;
                const int n = n0 + nt * 16 + lr;
                g16[(size_t)(b * CV_ + c) * N_ + n] = f2bf(ag[nt][reg] + g_b[c]);
            }
        }
    }
}

// ---------------------------------------------------------------------------
// Kernel 2: Z[b][j] = sum_i exp2(S[i][j]) via MFMA.
// ---------------------------------------------------------------------------
__global__ __launch_bounds__(256) void colstats_kernel(
    const u16* __restrict__ theta_t, const u16* __restrict__ phi_t,
    float* __restrict__ Z)
{
    const int b  = blockIdx.z;
    const int j0 = blockIdx.x * 32;
    const int istart = blockIdx.y * (N_ / 4);
    const int tid = threadIdx.x;
    const int wave = tid >> 6, lane = tid & 63;
    const int lr = lane & 15, q = lane >> 4;

    const int jW = j0 + (wave & 1) * 16;
    const short8 bF = *(const short8*)(phi_t + (size_t)(b * N_ + jW + lr) * CK_ + q * 8);

    const u16* thp = theta_t + (size_t)b * N_ * CK_;
    const f32x4 zero = {0.f, 0.f, 0.f, 0.f};
    float zacc = 0.f;
    for (int it = istart + (wave >> 1) * 16; it < istart + N_ / 4; it += 32) {
        const short8 aF = *(const short8*)(thp + (size_t)(it + lr) * CK_ + q * 8);
        f32x4 S = __builtin_amdgcn_mfma_f32_16x16x32_bf16(aF, bF, zero, 0, 0, 0);
        zacc += exp2f(S[0]) + exp2f(S[1]) + exp2f(S[2]) + exp2f(S[3]);
    }
    zacc += __shfl_xor(zacc, 16);
    zacc += __shfl_xor(zacc, 32);
    if (lane < 16) atomicAdd(&Z[(size_t)b * N_ + jW + lr], zacc);
}

// ---------------------------------------------------------------------------
// Kernel 3: fold 1/Z into g (in place, bf16). 8 elems/thread.
// Removes all Z work from opre's inner loop (R3-proven numerics).
// ---------------------------------------------------------------------------
__global__ __launch_bounds__(256) void gscale_kernel(
    u16* __restrict__ g16, const float* __restrict__ Z)
{
    const size_t idx = ((size_t)blockIdx.x * 256 + threadIdx.x) * 8;
    const int n = (int)(idx & (N_ - 1));
    const int b = (int)(idx / ((size_t)CV_ * N_));
    uint4 raw = *(const uint4*)(g16 + idx);
    const float4 z0 = *(const float4*)(Z + (size_t)b * N_ + n);
    const float4 z1 = *(const float4*)(Z + (size_t)b * N_ + n + 4);
    const float zz[8] = {z0.x, z0.y, z0.z, z0.w, z1.x, z1.y, z1.z, z1.w};
    u16* pr = (u16*)&raw;
    union { u16 us[8]; uint4 u4; } pk;
    #pragma unroll
    for (int k = 0; k < 8; ++k) pk.us[k] = f2bf(bf2f(pr[k]) / zz[k]);
    *(uint4*)(g16 + idx) = pk.u4;
}

// ---------------------------------------------------------------------------
// Kernel 4: o_pre partial = sum_{j in half} gp[c][j] * exp2(S[i][j]).
// R3's block-cooperative structure (the measured best) with halved LDS reads:
// Grid (N/64, 2 j-halves, B) = 512 blocks x 512 thr (8 waves).
// S-phase: wave (jt=w&3, it2=w>>2) computes S(32i x 16j) = 2 MFMAs -> exp2 ->
// scalar-u16 writes with R3's XOR swizzle (measured 0 bank conflicts).
// PV-phase: wave (cg=w&3, ig=w>>2) owns 32c x 32i: 8 MFMAs per chunk vs only
// 4 b128 E-reads (2:1, vs R3's 1:1) and 4 gA loads (each reused 2x).
// Double-buffered E, ONE barrier per 64-j chunk, reg-prefetched phi.
// ---------------------------------------------------------------------------
__global__ __launch_bounds__(512) void opre_kernel(
    const u16* __restrict__ theta_t, const u16* __restrict__ phi_t,
    const u16* __restrict__ g16, u16* __restrict__ o_p)
{
    const int b = blockIdx.z, jh = blockIdx.y, i0 = blockIdx.x * 64;
    const int w = threadIdx.x >> 6, lane = threadIdx.x & 63;
    const int lr = lane & 15, q = lane >> 4;

    __shared__ u16 El[2][64 * 64];                 // 2 x 8 KB

    // S-phase mapping
    const int jt = w & 3, it2 = w >> 2;
    const short8 aF0 = *(const short8*)(theta_t + (size_t)(b * N_ + i0 + it2 * 32 + lr) * CK_ + q * 8);
    const short8 aF1 = *(const short8*)(theta_t + (size_t)(b * N_ + i0 + it2 * 32 + 16 + lr) * CK_ + q * 8);

    // PV-phase mapping: wave owns c-block cg*32 (2 m-tiles) x i-block ig*32 (2 n-tiles)
    const int cg = w & 3, ig = w >> 2;
    const u16* gb = g16 + (size_t)(b * CV_ + cg * 32) * N_;

    f32x4 acc[2][2];
    #pragma unroll
    for (int mt = 0; mt < 2; ++mt)
        #pragma unroll
        for (int nt = 0; nt < 2; ++nt) acc[mt][nt] = (f32x4){0.f, 0.f, 0.f, 0.f};

    const f32x4 zf = {0.f, 0.f, 0.f, 0.f};
    const u16* pb = phi_t + (size_t)(b * N_) * CK_;
    const int jstart = jh * (N_ / 2), jend = jstart + N_ / 2;
    short8 bF = *(const short8*)(pb + (size_t)(jstart + jt * 16 + lr) * CK_ + q * 8);
    int buf = 0;

    for (int j0 = jstart; j0 < jend; j0 += 64) {
        const f32x4 S0 = __builtin_amdgcn_mfma_f32_16x16x32_bf16(aF0, bF, zf, 0, 0, 0);
        const f32x4 S1 = __builtin_amdgcn_mfma_f32_16x16x32_bf16(aF1, bF, zf, 0, 0, 0);

        // prefetch next chunk's phi frag (register double-buffer)
        const int jn = (j0 + 64 < jend) ? j0 + 64 : jstart;
        bF = *(const short8*)(pb + (size_t)(jn + jt * 16 + lr) * CK_ + q * 8);

        // E = exp2(S) -> LDS (bf16), R3 swizzle: phys chunk = (j>>3) ^ (i&7)
        u16* Eb = El[buf];
        const int jcol = jt * 16 + lr;
        #pragma unroll
        for (int reg = 0; reg < 4; ++reg) {
            const int ia = it2 * 32 + q * 4 + reg;
            Eb[ia * 64 + ((((jcol >> 3) ^ (ia & 7)) << 3) | (jcol & 7))] = f2bf(exp2f(S0[reg]));
            const int ib = ia + 16;
            Eb[ib * 64 + ((((jcol >> 3) ^ (ib & 7)) << 3) | (jcol & 7))] = f2bf(exp2f(S1[reg]));
        }
        __syncthreads();

        // PV: acc[mt][nt] += gp . E^T  (A = g m=c, B = E n=i, k=j)
        #pragma unroll
        for (int ks = 0; ks < 2; ++ks) {
            short8 bE[2];
            #pragma unroll
            for (int nt = 0; nt < 2; ++nt) {
                const int row = ig * 32 + nt * 16 + lr;
                bE[nt] = *(const short8*)(Eb + row * 64 + (((ks * 4 + q) ^ (row & 7)) << 3));
            }
            #pragma unroll
            for (int mt = 0; mt < 2; ++mt) {
                const short8 gA = *(const short8*)(gb + (size_t)(mt * 16 + lr) * N_ + j0 + ks * 32 + q * 8);
                acc[mt][0] = __builtin_amdgcn_mfma_f32_16x16x32_bf16(gA, bE[0], acc[mt][0], 0, 0, 0);
                acc[mt][1] = __builtin_amdgcn_mfma_f32_16x16x32_bf16(gA, bE[1], acc[mt][1], 0, 0, 0);
            }
        }
        buf ^= 1;
    }

    // epilogue: lane holds (c = cg*32 + mt*16 + q*4 + reg, i = i0 + ig*32 + nt*16 + lr)
    // direct bf16 [n][cv] partial stores, 8 B per lane.
    u16* op = o_p + (size_t)(jh * B_ + b) * N_ * CV_;
    #pragma unroll
    for (int mt = 0; mt < 2; ++mt) {
        #pragma unroll
        for (int nt = 0; nt < 2; ++nt) {
            union { u16 us[4]; uint2 u2; } pk;
            #pragma unroll
            for (int reg = 0; reg < 4; ++reg) pk.us[reg] = f2bf(acc[mt][nt][reg]);
            *(uint2*)(op + (size_t)(i0 + ig * 32 + nt * 16 + lr) * CV_ + cg * 32 + mt * 16 + q * 4) = pk.u2;
        }
    }
}

// ---------------------------------------------------------------------------
// Kernel 5: out = x + gamma * (o_w @ (o_p0 + o_p1) + o_b) via MFMA.
// Grid (N/64, 4 oc-quarters, B) = 1024 blocks. Wave: 1 oc m-tile x 64 n.
// ---------------------------------------------------------------------------
__global__ __launch_bounds__(256) void final_mfma_kernel(
    const u16* __restrict__ o_p, const u16* __restrict__ ow16,
    const float* __restrict__ o_b, const float* __restrict__ gamma,
    const float* __restrict__ x, float* __restrict__ out)
{
    const int b = blockIdx.z, ych = blockIdx.y, n0 = blockIdx.x * 64;
    const int w = threadIdx.x >> 6, lane = threadIdx.x & 63;
    const int lr = lane & 15, q = lane >> 4;
    const size_t PSTRIDE = (size_t)B_ * N_ * CV_;

    f32x4 acc[4];
    #pragma unroll
    for (int nt = 0; nt < 4; ++nt) acc[nt] = (f32x4){0.f, 0.f, 0.f, 0.f};

    const int ocb = ych * 64 + w * 16;

    for (int ks = 0; ks < 4; ++ks) {
        const short8 aW = *(const short8*)(ow16 + (size_t)(ocb + lr) * CV_ + ks * 32 + q * 8);
        #pragma unroll
        for (int nt = 0; nt < 4; ++nt) {
            const size_t pbase = (size_t)(b * N_ + n0 + nt * 16 + lr) * CV_ + ks * 32 + q * 8;
            const uint4 r0 = *(const uint4*)(o_p + pbase);
            const uint4 r1 = *(const uint4*)(o_p + PSTRIDE + pbase);
            const u16* p0 = (const u16*)&r0;
            const u16* p1 = (const u16*)&r1;
            union { u16 us[8]; short8 s8; } pk;
            #pragma unroll
            for (int e = 0; e < 8; ++e) pk.us[e] = f2bf(bf2f(p0[e]) + bf2f(p1[e]));
            acc[nt] = __builtin_amdgcn_mfma_f32_16x16x32_bf16(aW, pk.s8, acc[nt], 0, 0, 0);
        }
    }

    const float gm = gamma[0];
    #pragma unroll
    for (int nt = 0; nt < 4; ++nt) {
        #pragma unroll
        for (int reg = 0; reg < 4; ++reg) {
            const int oc = ocb + q * 4 + reg;
            const int n = n0 + nt * 16 + lr;
            const size_t off = (size_t)(b * C_ + oc) * N_ + n;
            out[off] = x[off] + gm * (acc[nt][reg] + o_b[oc]);
        }
    }
}

// ---------------------------------------------------------------------------
extern "C" void kernel_launch(void* const* d_in, const int* in_sizes, int n_in,
                              void* d_out, int out_size, void* d_ws, size_t ws_size,
                              hipStream_t stream)
{
    const float* x       = (const float*)d_in[0];
    const float* theta_w = (const float*)d_in[1];
    const float* theta_b = (const float*)d_in[2];
    const float* phi_w   = (const float*)d_in[3];
    const float* phi_b   = (const float*)d_in[4];
    const float* g_w     = (const float*)d_in[5];
    const float* g_b     = (const float*)d_in[6];
    const float* o_w     = (const float*)d_in[7];
    const float* o_b     = (const float*)d_in[8];
    const float* gamma   = (const float*)d_in[9];
    float* out = (float*)d_out;

    // workspace: xT16 8MB | W16 96KB | ow16 64KB | theta_t 1MB | phi_t 1MB |
    //            g16 4MB | Z 64KB | o_p 2x4MB bf16 = 8MB   (~22.2 MB)
    u16* xT16    = (u16*)d_ws;
    u16* W16     = xT16 + (size_t)B_ * N_ * C_;
    u16* ow16    = W16 + 192 * C_;
    u16* theta_t = ow16 + C_ * CV_;
    u16* phi_t   = theta_t + (size_t)B_ * N_ * CK_;
    u16* g16     = phi_t + (size_t)B_ * N_ * CK_;
    float* Z     = (float*)(g16 + (size_t)B_ * CV_ * N_);
    u16* o_p     = (u16*)(Z + (size_t)B_ * N_);

    (void)hipMemsetAsync(Z, 0, (size_t)B_ * N_ * sizeof(float), stream);

    wconv_kernel<<<dim3(320), 256, 0, stream>>>(theta_w, phi_w, g_w, o_w, W16, ow16);
    xt_kernel<<<dim3(N_ / 64, C_ / 64, B_), 256, 0, stream>>>(x, xT16);
    proj_mfma_kernel<<<dim3(N_ / 64, 3, B_), 256, 0, stream>>>(
        xT16, W16, theta_b, phi_b, g_b, theta_t, phi_t, g16);
    colstats_kernel<<<dim3(N_ / 32, 4, B_), 256, 0, stream>>>(theta_t, phi_t, Z);
    gscale_kernel<<<dim3((B_ * CV_ * N_) / 2048), 256, 0, stream>>>(g16, Z);
    opre_kernel<<<dim3(N_ / 64, 2, B_), 512, 0, stream>>>(theta_t, phi_t, g16, o_p);
    final_mfma_kernel<<<dim3(N_ / 64, 4, B_), 256, 0, stream>>>(
        o_p, ow16, o_b, gamma, x, out);
}